// Round 11
// baseline (142.723 us; speedup 1.0000x reference)
//
#include <hip/hip_runtime.h>
#include <stdint.h>
#include <stddef.h>

#define Tdim 4096
#define Hdim 2048

typedef short short8 __attribute__((ext_vector_type(8)));
typedef float floatx4 __attribute__((ext_vector_type(4)));

// RNE fp32 -> bf16 bit pattern
__device__ __forceinline__ unsigned short f2bf(float f) {
  uint32_t u = __float_as_uint(f);
  u += 0x7fffu + ((u >> 16) & 1u);
  return (unsigned short)(u >> 16);
}

// async global->LDS, 16B per lane. LDS dest is wave-uniform base + lane*16.
__device__ __forceinline__ void load_lds16(const void* g, void* l) {
  __builtin_amdgcn_global_load_lds(
      (__attribute__((address_space(1))) unsigned int*)(uintptr_t)g,
      (__attribute__((address_space(3))) unsigned int*)l,
      16, 0, 0);
}

__device__ __forceinline__ float tanh_fast(float z) {
  float e = __expf(z + z);
  return 1.0f - __fdividef(2.0f, e + 1.0f);
}

// aligned LDS vector read (forces ds_read_b128)
__device__ __forceinline__ short8 lds_read8(const unsigned short* p) {
  return *(const short8*)__builtin_assume_aligned(p, 16);
}

#define BARM() asm volatile("s_barrier" ::: "memory")
#define WAITV(N) asm volatile("s_waitcnt vmcnt(" #N ")" ::: "memory")
// rule-18: lgkmcnt(0) must be followed by sched_barrier(0) or hipcc hoists
// register-only MFMA above the wait.
#define LGKM0()                                                        \
  do {                                                                 \
    asm volatile("s_waitcnt lgkmcnt(0)" ::: "memory");                 \
    __builtin_amdgcn_sched_barrier(0);                                 \
  } while (0)

// Explicit barrier-with-drain (r16 lesson) — used outside the K-loop only.
#define SYNC_DRAIN()                                                   \
  do {                                                                 \
    asm volatile("s_waitcnt vmcnt(0) lgkmcnt(0)" ::: "memory");        \
    __syncthreads();                                                   \
  } while (0)

// ---- fused convert: blocks [0,4096) cast x -> bf16; blocks [4096,5120)
// transpose+cast b (HxH fp32, [k][n]) -> bt bf16 (N x K, [n][k]) ----
__global__ __launch_bounds__(256) void cvt_kernel(const float* __restrict__ x,
                                                  const float* __restrict__ b,
                                                  unsigned short* __restrict__ xbf,
                                                  unsigned short* __restrict__ bt) {
  __shared__ unsigned short tile[64 * 65];
  const int t = threadIdx.x;
  if (blockIdx.x < 4096) {
    size_t i = ((size_t)blockIdx.x * 256 + t) * 8;
    float4 f0 = *(const float4*)(x + i);
    float4 f1 = *(const float4*)(x + i + 4);
    union { unsigned short u[8]; uint4 v; } o;
    o.u[0] = f2bf(f0.x); o.u[1] = f2bf(f0.y); o.u[2] = f2bf(f0.z); o.u[3] = f2bf(f0.w);
    o.u[4] = f2bf(f1.x); o.u[5] = f2bf(f1.y); o.u[6] = f2bf(f1.z); o.u[7] = f2bf(f1.w);
    *(uint4*)(xbf + i) = o.v;
    return;
  }
  const int tb = blockIdx.x - 4096;
  const int bj = tb & 31;  // n block
  const int bi = tb >> 5;  // k block
  {
    const int r0 = t >> 4, c4 = (t & 15) * 4;
#pragma unroll
    for (int p = 0; p < 4; ++p) {
      int r = r0 + p * 16;
      float4 v = *(const float4*)(b + (size_t)(bi * 64 + r) * Hdim + bj * 64 + c4);
      tile[r * 65 + c4 + 0] = f2bf(v.x);
      tile[r * 65 + c4 + 1] = f2bf(v.y);
      tile[r * 65 + c4 + 2] = f2bf(v.z);
      tile[r * 65 + c4 + 3] = f2bf(v.w);
    }
  }
  __syncthreads();
  {
    const int n = t >> 2, kq = (t & 3) * 16;
    union { unsigned short u[16]; uint4 v[2]; } o;
#pragma unroll
    for (int q = 0; q < 16; ++q) o.u[q] = tile[(kq + q) * 65 + n];
    uint4* dst = (uint4*)(bt + (size_t)(bj * 64 + n) * Hdim + bi * 64 + kq);
    dst[0] = o.v[0];
    dst[1] = o.v[1];
  }
}

// ---- GEMM (s = x @ b) with fused windowed-scan epilogue ----
// Round 22 (resubmit; r22 never ran -- broker timeout): faithful 8-phase
// counted-vmcnt port (T3+T4+T5) on the r21 geometry. The 2-phase ledger
// (r12/r17/r21: 44-47us regardless of tile geometry) matches m233's
// diagnosis: stage+vmcnt(0)+barrier = ~72% of the 2-phase critical path.
// Fix = m201's fine interleave:
//   per K-tile, 4 phases, each {<=6 ds_read_b128 || 2 glds for tile t+2}
//   -> barrier -> lgkmcnt(0)+sched_barrier -> setprio(1) -> 8 MFMA ->
//   setprio(0) -> barrier.
//   3 LDS buffers, 2-tile-deep prefetch; boundary wait ONCE per K-tile:
//   vmcnt(6) (wave7: 7, incl warm) -- loads for t+2 stay in flight across
//   the barrier; vmcnt(0) only at t=30. (r13's failure was the COARSE
//   split -- all 16 MFMA + all reads clumped, m196's -7..-27% trap.)
//
// Geometry (r21, correctness-proven): BM=256 x BN=128, BK=64, 8 waves x
// 64x64 wave-tile (4x4 frags of 16x16x32), XOR swizzle (slot (row,chunk)
// holds global chunk c^(row&7), applied on the fetch column; fragment
// reads XOR the same term -> conflict-free), XCD = bm%8 (2MB A per XCD,
// L2-resident), warm rows (8 extra A rows staged by wave 7, MFMA'd by
// waves 0,1), s_tile 264x129 scan epilogue (8-row warmup, |a|<=0.03125
// -> window error < 1e-12).
__global__ __launch_bounds__(512, 2) void gemm_scan_kernel(const unsigned short* __restrict__ A,
                                                           const unsigned short* __restrict__ Bt,
                                                           const float* __restrict__ a_mat,
                                                           float* __restrict__ out) {
  // alignas(16) REQUIRED for short8 LDS reads to stay ds_read_b128.
  __shared__ alignas(16) union SM {
    struct {
      unsigned short sA[3][256 * 64];   // 3 x 32 KB
      unsigned short sB[3][128 * 64];   // 3 x 16 KB
      unsigned short sAw[3][8 * 64];    // 3 x 1 KB
    } st;                      // 147 KB
    float s_tile[264 * 129];   // 136.2 KB; [row][col], pad 129
  } sm;

  const int tid = threadIdx.x;
  const int bm = blockIdx.x, bn = blockIdx.y;  // bm fastest -> XCD = bm%8
  const int wave = tid >> 6, lane = tid & 63;
  const int wm = (wave >> 1) * 64;   // 0,0,64,64,128,128,192,192
  const int wn = (wave & 1) * 64;    // 0,64
  const int l15 = lane & 15, quad = lane >> 4;
  const int l7 = l15 & 7;

  // staging: thread tid fills LDS slot (row = tid>>3 + 64c, chunk = tid&7)
  // holding global chunk (tid&7)^(row&7); rows advance 64 == 0 mod 8 per
  // c-chunk -> XOR term constant per thread.
  const int swz = ((tid & 7) ^ ((tid >> 3) & 7)) * 8;
  const unsigned short* aSrc = A + ((size_t)(bm * 256 + (tid >> 3)) * Hdim + swz);
  const unsigned short* bSrc = Bt + ((size_t)(bn * 128 + (tid >> 3)) * Hdim + swz);
  const int tw0 = (bm > 0) ? bm * 256 - 8 : 0;  // clamp keeps address valid
  const int wswz = ((lane & 7) ^ ((lane >> 3) & 7)) * 8;
  const unsigned short* wSrc = A + ((size_t)(tw0 + (lane >> 3)) * Hdim + wswz);

  floatx4 acc[4][4] = {};
  floatx4 accw[4] = {};

  const int c0 = (quad ^ l7) * 8;  // kk=0 chunk offset (shorts)
  const int c1 = c0 ^ 32;          // kk=32
  int rA[4], rB[4];
#pragma unroll
  for (int i = 0; i < 4; ++i) rA[i] = (wm + i * 16 + l15) * 64;
#pragma unroll
  for (int j = 0; j < 4; ++j) rB[j] = (wn + j * 16 + l15) * 64;
  const int rW = l7 * 64;

  // full-tile stage (prologue only): 4 A-chunks + 2 B-chunks (+warm on w7)
  auto stage_full = [&](int nb, int k0) {
    unsigned short* aDst = &sm.st.sA[nb][tid * 8];
    unsigned short* bDst = &sm.st.sB[nb][tid * 8];
#pragma unroll
    for (int c = 0; c < 4; ++c)
      load_lds16(aSrc + (size_t)c * 64 * Hdim + k0, aDst + c * 4096);
#pragma unroll
    for (int c = 0; c < 2; ++c)
      load_lds16(bSrc + (size_t)c * 64 * Hdim + k0, bDst + c * 4096);
    if (wave == 7) load_lds16(wSrc + k0, &sm.st.sAw[nb][lane * 8]);
  };

  // prologue: tiles 0,1 staged; wait own tile-0 loads (leave tile 1's)
  stage_full(0, 0);
  stage_full(1, 64);
  if (wave == 7) { WAITV(7); } else { WAITV(6); }
  BARM();

  int buf = 0;  // = t % 3
  for (int t = 0; t < 32; ++t) {
    const int nb = (buf >= 1) ? buf - 1 : 2;  // (t+2) % 3
    const bool pf = (t < 30);
    const int k2 = (t + 2) * 64;
    const unsigned short* sAb = sm.st.sA[buf];
    const unsigned short* sBb = sm.st.sB[buf];
    const unsigned short* sWb = sm.st.sAw[buf];
    unsigned short* aDst = &sm.st.sA[nb][tid * 8];
    unsigned short* bDst = &sm.st.sB[nb][tid * 8];

    short8 av[4], bv[4], aw = {};

    // ---- P0: kk=0, j=0,1 ---- (6 reads | 2 A-glds | 8 MFMA)
#pragma unroll
    for (int i = 0; i < 4; ++i) av[i] = lds_read8(sAb + rA[i] + c0);
    bv[0] = lds_read8(sBb + rB[0] + c0);
    bv[1] = lds_read8(sBb + rB[1] + c0);
    if (pf) {
      load_lds16(aSrc + k2, aDst);
      load_lds16(aSrc + (size_t)64 * Hdim + k2, aDst + 4096);
    }
    BARM();
    LGKM0();
    __builtin_amdgcn_s_setprio(1);
#pragma unroll
    for (int i = 0; i < 4; ++i) {
      acc[i][0] = __builtin_amdgcn_mfma_f32_16x16x32_bf16(av[i], bv[0], acc[i][0], 0, 0, 0);
      acc[i][1] = __builtin_amdgcn_mfma_f32_16x16x32_bf16(av[i], bv[1], acc[i][1], 0, 0, 0);
    }
    __builtin_amdgcn_s_setprio(0);
    BARM();

    // ---- P1: kk=0, j=2,3 (+warm) ---- (2-3 reads | 2 A-glds | 8-12 MFMA)
    bv[2] = lds_read8(sBb + rB[2] + c0);
    bv[3] = lds_read8(sBb + rB[3] + c0);
    if (wm == 0) aw = lds_read8(sWb + rW + c0);
    if (pf) {
      load_lds16(aSrc + (size_t)128 * Hdim + k2, aDst + 8192);
      load_lds16(aSrc + (size_t)192 * Hdim + k2, aDst + 12288);
    }
    BARM();
    LGKM0();
    __builtin_amdgcn_s_setprio(1);
#pragma unroll
    for (int i = 0; i < 4; ++i) {
      acc[i][2] = __builtin_amdgcn_mfma_f32_16x16x32_bf16(av[i], bv[2], acc[i][2], 0, 0, 0);
      acc[i][3] = __builtin_amdgcn_mfma_f32_16x16x32_bf16(av[i], bv[3], acc[i][3], 0, 0, 0);
    }
    if (wm == 0) {
#pragma unroll
      for (int j = 0; j < 4; ++j)
        accw[j] = __builtin_amdgcn_mfma_f32_16x16x32_bf16(aw, bv[j], accw[j], 0, 0, 0);
    }
    __builtin_amdgcn_s_setprio(0);
    BARM();

    // ---- P2: kk=32, j=0,1 ---- (6 reads | 2 B-glds | 8 MFMA)
#pragma unroll
    for (int i = 0; i < 4; ++i) av[i] = lds_read8(sAb + rA[i] + c1);
    bv[0] = lds_read8(sBb + rB[0] + c1);
    bv[1] = lds_read8(sBb + rB[1] + c1);
    if (pf) {
      load_lds16(bSrc + k2, bDst);
      load_lds16(bSrc + (size_t)64 * Hdim + k2, bDst + 4096);
    }
    BARM();
    LGKM0();
    __builtin_amdgcn_s_setprio(1);
#pragma unroll
    for (int i = 0; i < 4; ++i) {
      acc[i][0] = __builtin_amdgcn_mfma_f32_16x16x32_bf16(av[i], bv[0], acc[i][0], 0, 0, 0);
      acc[i][1] = __builtin_amdgcn_mfma_f32_16x16x32_bf16(av[i], bv[1], acc[i][1], 0, 0, 0);
    }
    __builtin_amdgcn_s_setprio(0);
    BARM();

    // ---- P3: kk=32, j=2,3 (+warm) ---- (2-3 reads | warm glds | 8-12 MFMA)
    bv[2] = lds_read8(sBb + rB[2] + c1);
    bv[3] = lds_read8(sBb + rB[3] + c1);
    if (wm == 0) aw = lds_read8(sWb + rW + c1);
    if (pf && wave == 7) load_lds16(wSrc + k2, &sm.st.sAw[nb][lane * 8]);
    BARM();
    LGKM0();
    __builtin_amdgcn_s_setprio(1);
#pragma unroll
    for (int i = 0; i < 4; ++i) {
      acc[i][2] = __builtin_amdgcn_mfma_f32_16x16x32_bf16(av[i], bv[2], acc[i][2], 0, 0, 0);
      acc[i][3] = __builtin_amdgcn_mfma_f32_16x16x32_bf16(av[i], bv[3], acc[i][3], 0, 0, 0);
    }
    if (wm == 0) {
#pragma unroll
      for (int j = 0; j < 4; ++j)
        accw[j] = __builtin_amdgcn_mfma_f32_16x16x32_bf16(aw, bv[j], accw[j], 0, 0, 0);
    }
    __builtin_amdgcn_s_setprio(0);
    // tile boundary: complete tile t+1's DMA, keep t+2's in flight
    if (t < 30) {
      if (wave == 7) { WAITV(7); } else { WAITV(6); }
    } else if (t == 30) {
      WAITV(0);
    }
    BARM();
    buf = (buf == 2) ? 0 : buf + 1;
  }
  SYNC_DRAIN();  // union repurpose: all counters drained before s_tile

  // ---- epilogue: registers -> s_tile (C/D layout: col=lane&15, row=quad*4+r) ----
  if (wm == 0 && quad < 2) {  // warm rows idx 0..7
#pragma unroll
    for (int j = 0; j < 4; ++j)
#pragma unroll
      for (int r = 0; r < 4; ++r)
        sm.s_tile[(quad * 4 + r) * 129 + wn + j * 16 + l15] = accw[j][r];
  }
#pragma unroll
  for (int i = 0; i < 4; ++i)
#pragma unroll
    for (int j = 0; j < 4; ++j)
#pragma unroll
      for (int r = 0; r < 4; ++r)
        sm.s_tile[(8 + wm + i * 16 + quad * 4 + r) * 129 + wn + j * 16 + l15] = acc[i][j][r];
  SYNC_DRAIN();

  // ---- windowed scan: 512 threads = 128 cols x 4 chunks of 64 rows ----
  const int col = tid & 127;
  const int chunk = tid >> 7;
  const float aj = a_mat[bn * 128 + col];
  float h = 0.0f;
  const int row0 = 8 + chunk * 64;
  if (!(bm == 0 && chunk == 0)) {
#pragma unroll
    for (int r = row0 - 8; r < row0; ++r)  // warm-up (discarded outputs)
      h = tanh_fast(fmaf(aj, h, sm.s_tile[r * 129 + col]));
  }
  const size_t gbase = (size_t)(bm * 256 + chunk * 64) * Hdim + bn * 128 + col;
#pragma unroll 4
  for (int r2 = 0; r2 < 64; ++r2) {
    h = tanh_fast(fmaf(aj, h, sm.s_tile[(row0 + r2) * 129 + col]));
    out[gbase + (size_t)r2 * Hdim] = h;
  }
}

extern "C" void kernel_launch(void* const* d_in, const int* in_sizes, int n_in,
                              void* d_out, int out_size, void* d_ws, size_t ws_size,
                              hipStream_t stream) {
  const float* x = (const float*)d_in[0];
  const float* a = (const float*)d_in[1];
  const float* b = (const float*)d_in[2];
  float* out = (float*)d_out;

  unsigned short* ws = (unsigned short*)d_ws;
  unsigned short* xbf = ws;                                 // 16.8 MB
  unsigned short* btb = xbf + (size_t)Tdim * Hdim;          // 8.4 MB

  hipLaunchKernelGGL(cvt_kernel, dim3(4096 + (Hdim / 64) * (Hdim / 64)), dim3(256), 0, stream,
                     x, b, xbf, btb);
  // grid: x = bm (16, fastest -> XCD = bm%8), y = bn (16); 256 blocks = 1/CU
  hipLaunchKernelGGL(gemm_scan_kernel, dim3(Tdim / 256, Hdim / 128), dim3(512), 0, stream,
                     xbf, btb, a, out);
}

// Round 13
// 141.302 us; speedup vs baseline: 1.0101x; 1.0101x over previous
//
#include <hip/hip_runtime.h>
#include <stdint.h>
#include <stddef.h>

#define Tdim 4096
#define Hdim 2048

typedef short short8 __attribute__((ext_vector_type(8)));
typedef float floatx4 __attribute__((ext_vector_type(4)));

// RNE fp32 -> bf16 bit pattern
__device__ __forceinline__ unsigned short f2bf(float f) {
  uint32_t u = __float_as_uint(f);
  u += 0x7fffu + ((u >> 16) & 1u);
  return (unsigned short)(u >> 16);
}

// async global->LDS, 16B per lane. LDS dest is wave-uniform base + lane*16.
__device__ __forceinline__ void load_lds16(const void* g, void* l) {
  __builtin_amdgcn_global_load_lds(
      (__attribute__((address_space(1))) unsigned int*)(uintptr_t)g,
      (__attribute__((address_space(3))) unsigned int*)l,
      16, 0, 0);
}

__device__ __forceinline__ float tanh_fast(float z) {
  float e = __expf(z + z);
  return 1.0f - __fdividef(2.0f, e + 1.0f);
}

// aligned LDS vector read (forces ds_read_b128)
__device__ __forceinline__ short8 lds_read8(const unsigned short* p) {
  return *(const short8*)__builtin_assume_aligned(p, 16);
}

#define BARM() asm volatile("s_barrier" ::: "memory")
#define WAITV(N) asm volatile("s_waitcnt vmcnt(" #N ")" ::: "memory")

// Explicit barrier-with-drain (r16 lesson) — outside the K-loop only.
#define SYNC_DRAIN()                                                   \
  do {                                                                 \
    asm volatile("s_waitcnt vmcnt(0) lgkmcnt(0)" ::: "memory");        \
    __syncthreads();                                                   \
  } while (0)

// ---- fused convert: blocks [0,4096) cast x -> bf16; blocks [4096,5120)
// transpose+cast b (HxH fp32, [k][n]) -> bt bf16 (N x K, [n][k]) ----
__global__ __launch_bounds__(256) void cvt_kernel(const float* __restrict__ x,
                                                  const float* __restrict__ b,
                                                  unsigned short* __restrict__ xbf,
                                                  unsigned short* __restrict__ bt) {
  __shared__ unsigned short tile[64 * 65];
  const int t = threadIdx.x;
  if (blockIdx.x < 4096) {
    size_t i = ((size_t)blockIdx.x * 256 + t) * 8;
    float4 f0 = *(const float4*)(x + i);
    float4 f1 = *(const float4*)(x + i + 4);
    union { unsigned short u[8]; uint4 v; } o;
    o.u[0] = f2bf(f0.x); o.u[1] = f2bf(f0.y); o.u[2] = f2bf(f0.z); o.u[3] = f2bf(f0.w);
    o.u[4] = f2bf(f1.x); o.u[5] = f2bf(f1.y); o.u[6] = f2bf(f1.z); o.u[7] = f2bf(f1.w);
    *(uint4*)(xbf + i) = o.v;
    return;
  }
  const int tb = blockIdx.x - 4096;
  const int bj = tb & 31;  // n block
  const int bi = tb >> 5;  // k block
  {
    const int r0 = t >> 4, c4 = (t & 15) * 4;
#pragma unroll
    for (int p = 0; p < 4; ++p) {
      int r = r0 + p * 16;
      float4 v = *(const float4*)(b + (size_t)(bi * 64 + r) * Hdim + bj * 64 + c4);
      tile[r * 65 + c4 + 0] = f2bf(v.x);
      tile[r * 65 + c4 + 1] = f2bf(v.y);
      tile[r * 65 + c4 + 2] = f2bf(v.z);
      tile[r * 65 + c4 + 3] = f2bf(v.w);
    }
  }
  __syncthreads();
  {
    const int n = t >> 2, kq = (t & 3) * 16;
    union { unsigned short u[16]; uint4 v[2]; } o;
#pragma unroll
    for (int q = 0; q < 16; ++q) o.u[q] = tile[(kq + q) * 65 + n];
    uint4* dst = (uint4*)(bt + (size_t)(bj * 64 + n) * Hdim + bi * 64 + kq);
    dst[0] = o.v[0];
    dst[1] = o.v[1];
  }
}

// ---- GEMM (s = x @ b) with fused windowed-scan epilogue ----
// Round 23 (resubmit; r23 never ran -- broker timeout): T4 in ISOLATION.
// Ledger: 2-phase drain0 (r12/r17/r21) = 44-47us across 3 geometries;
// 8-phase counted (r22) = 52.5us (128 barriers/block with 1 block/CU
// lockstep + 8-12-MFMA phases too short -- the T3 split cost more than it
// saved). m218: "T3's gain IS T4" -> test counted-vmcnt alone on the
// proven r21 loop:
//   3 LDS buffers, 2-tile-deep prefetch. Per K-tile: issue stage(t+2)
//   (6 glds/thread; wave7: 7 incl warm), compute(t) MONOLITHIC (ds_read +
//   MFMA interleaved by the compiler -- the proven r21 body, no phase
//   barriers), then wait vmcnt(6) (w7: 7) -- completes exactly tile t+1's
//   DMA, leaves t+2's in flight across the ONE barrier per K-tile.
//   vmcnt(0) only at t=30. Counting scheme + 3-buffer rotation are
//   correctness-validated by r22's passing run; compute body by r21's.
//
// Geometry (r21, proven): BM=256 x BN=128, BK=64, 8 waves x 64x64
// wave-tile (4x4 frags of 16x16x32). XOR swizzle: slot (row, chunk c)
// holds global chunk c^(row&7), applied on the fetch column (wave-uniform
// contiguous glds dest preserved); fragment reads XOR the same term ->
// conflict-free ds_read_b128. XCD = bm%8 (2MB A per XCD, L2-resident).
// Warm rows: 8 extra A rows staged by wave 7, MFMA'd by waves 0,1.
// Epilogue: acc -> s_tile (264x129 fp32) -> 512 threads scan 128 cols x
// 4 chunks of 64 rows, 8-row warmup (|a| <= 0.03125 -> window error
// < 1e-12) -> out. No s buffer in HBM.
__global__ __launch_bounds__(512, 2) void gemm_scan_kernel(const unsigned short* __restrict__ A,
                                                           const unsigned short* __restrict__ Bt,
                                                           const float* __restrict__ a_mat,
                                                           float* __restrict__ out) {
  // alignas(16) REQUIRED for short8 LDS reads to stay ds_read_b128.
  __shared__ alignas(16) union SM {
    struct {
      unsigned short sA[3][256 * 64];   // 3 x 32 KB
      unsigned short sB[3][128 * 64];   // 3 x 16 KB
      unsigned short sAw[3][8 * 64];    // 3 x 1 KB
    } st;                      // 147 KB
    float s_tile[264 * 129];   // 136.2 KB; [row][col], pad 129
  } sm;

  const int tid = threadIdx.x;
  const int bm = blockIdx.x, bn = blockIdx.y;  // bm fastest -> XCD = bm%8
  const int wave = tid >> 6, lane = tid & 63;
  const int wm = (wave >> 1) * 64;   // 0,0,64,64,128,128,192,192
  const int wn = (wave & 1) * 64;    // 0,64
  const int l15 = lane & 15, quad = lane >> 4;
  const int l7 = l15 & 7;

  // staging: thread tid fills LDS slot (row = tid>>3 + 64c, chunk = tid&7)
  // holding global chunk (tid&7)^(row&7); rows advance 64 == 0 mod 8 per
  // c-chunk -> XOR term constant per thread.
  const int swz = ((tid & 7) ^ ((tid >> 3) & 7)) * 8;
  const unsigned short* aSrc = A + ((size_t)(bm * 256 + (tid >> 3)) * Hdim + swz);
  const unsigned short* bSrc = Bt + ((size_t)(bn * 128 + (tid >> 3)) * Hdim + swz);
  const int tw0 = (bm > 0) ? bm * 256 - 8 : 0;  // clamp keeps address valid
  const int wswz = ((lane & 7) ^ ((lane >> 3) & 7)) * 8;
  const unsigned short* wSrc = A + ((size_t)(tw0 + (lane >> 3)) * Hdim + wswz);

  floatx4 acc[4][4] = {};
  floatx4 accw[4] = {};

  // stage tile (k0) into buffer `nb`: 6 glds/thread (wave 7: +1 warm)
  auto stage = [&](int nb, int k0) {
    unsigned short* aDst = &sm.st.sA[nb][tid * 8];
    unsigned short* bDst = &sm.st.sB[nb][tid * 8];
#pragma unroll
    for (int c = 0; c < 4; ++c)
      load_lds16(aSrc + (size_t)c * 64 * Hdim + k0, aDst + c * 4096);
#pragma unroll
    for (int c = 0; c < 2; ++c)
      load_lds16(bSrc + (size_t)c * 64 * Hdim + k0, bDst + c * 4096);
    if (wave == 7) load_lds16(wSrc + k0, &sm.st.sAw[nb][lane * 8]);
  };

  // compute from buffer `buf`: wave-tile 64x64 -> 4x4 frags x 2 kk-steps
  // (monolithic: compiler interleaves ds_read and MFMA -- the proven body)
  auto compute = [&](int buf) {
#pragma unroll
    for (int kk = 0; kk < 64; kk += 32) {
      const int coff = (((kk >> 3) + quad) ^ l7) * 8;
      short8 av[4], bv[4];
#pragma unroll
      for (int i = 0; i < 4; ++i)
        av[i] = lds_read8(&sm.st.sA[buf][(wm + i * 16 + l15) * 64 + coff]);
#pragma unroll
      for (int j = 0; j < 4; ++j)
        bv[j] = lds_read8(&sm.st.sB[buf][(wn + j * 16 + l15) * 64 + coff]);
#pragma unroll
      for (int i = 0; i < 4; ++i)
#pragma unroll
        for (int j = 0; j < 4; ++j)
          acc[i][j] = __builtin_amdgcn_mfma_f32_16x16x32_bf16(av[i], bv[j], acc[i][j], 0, 0, 0);
      if (wm == 0) {  // warm rows: waves 0,1 (wn 0/64), 4 j-frags each
        short8 aw = lds_read8(&sm.st.sAw[buf][l7 * 64 + coff]);
#pragma unroll
        for (int j = 0; j < 4; ++j)
          accw[j] = __builtin_amdgcn_mfma_f32_16x16x32_bf16(aw, bv[j], accw[j], 0, 0, 0);
      }
    }
  };

  // prologue: tiles 0,1 staged; wait tile-0's loads only (leave tile-1's
  // 6-7 in flight), then barrier.
  stage(0, 0);
  stage(1, 64);
  if (wave == 7) { WAITV(7); } else { WAITV(6); }
  BARM();

  int buf = 0;  // = t % 3
  for (int t = 0; t < 32; ++t) {
    const int nb = (buf >= 1) ? buf - 1 : 2;  // (t+2) % 3
    if (t < 30) stage(nb, (t + 2) * 64);      // issue BEFORE compute (T3 recipe)
    compute(buf);
    // boundary: complete tile t+1's DMA, keep t+2's in flight (T4)
    if (t < 30) {
      if (wave == 7) { WAITV(7); } else { WAITV(6); }
    } else if (t == 30) {
      WAITV(0);
    }
    BARM();
    buf = (buf == 2) ? 0 : buf + 1;
  }
  SYNC_DRAIN();  // union repurpose: all counters drained before s_tile

  // ---- epilogue: registers -> s_tile (C/D layout: col=lane&15, row=quad*4+r) ----
  if (wm == 0 && quad < 2) {  // warm rows idx 0..7
#pragma unroll
    for (int j = 0; j < 4; ++j)
#pragma unroll
      for (int r = 0; r < 4; ++r)
        sm.s_tile[(quad * 4 + r) * 129 + wn + j * 16 + l15] = accw[j][r];
  }
#pragma unroll
  for (int i = 0; i < 4; ++i)
#pragma unroll
    for (int j = 0; j < 4; ++j)
#pragma unroll
      for (int r = 0; r < 4; ++r)
        sm.s_tile[(8 + wm + i * 16 + quad * 4 + r) * 129 + wn + j * 16 + l15] = acc[i][j][r];
  SYNC_DRAIN();

  // ---- windowed scan: 512 threads = 128 cols x 4 chunks of 64 rows ----
  const int col = tid & 127;
  const int chunk = tid >> 7;
  const float aj = a_mat[bn * 128 + col];
  float h = 0.0f;
  const int row0 = 8 + chunk * 64;
  if (!(bm == 0 && chunk == 0)) {
#pragma unroll
    for (int r = row0 - 8; r < row0; ++r)  // warm-up (discarded outputs)
      h = tanh_fast(fmaf(aj, h, sm.s_tile[r * 129 + col]));
  }
  const size_t gbase = (size_t)(bm * 256 + chunk * 64) * Hdim + bn * 128 + col;
#pragma unroll 4
  for (int r2 = 0; r2 < 64; ++r2) {
    h = tanh_fast(fmaf(aj, h, sm.s_tile[(row0 + r2) * 129 + col]));
    out[gbase + (size_t)r2 * Hdim] = h;
  }
}

extern "C" void kernel_launch(void* const* d_in, const int* in_sizes, int n_in,
                              void* d_out, int out_size, void* d_ws, size_t ws_size,
                              hipStream_t stream) {
  const float* x = (const float*)d_in[0];
  const float* a = (const float*)d_in[1];
  const float* b = (const float*)d_in[2];
  float* out = (float*)d_out;

  unsigned short* ws = (unsigned short*)d_ws;
  unsigned short* xbf = ws;                                 // 16.8 MB
  unsigned short* btb = xbf + (size_t)Tdim * Hdim;          // 8.4 MB

  hipLaunchKernelGGL(cvt_kernel, dim3(4096 + (Hdim / 64) * (Hdim / 64)), dim3(256), 0, stream,
                     x, b, xbf, btb);
  // grid: x = bm (16, fastest -> XCD = bm%8), y = bn (16); 256 blocks = 1/CU
  hipLaunchKernelGGL(gemm_scan_kernel, dim3(Tdim / 256, Hdim / 128), dim3(512), 0, stream,
                     xbf, btb, a, out);
}

// Round 14
// 136.415 us; speedup vs baseline: 1.0462x; 1.0358x over previous
//
#include <hip/hip_runtime.h>
#include <stdint.h>
#include <stddef.h>

#define Tdim 4096
#define Hdim 2048

typedef short short8 __attribute__((ext_vector_type(8)));
typedef float floatx4 __attribute__((ext_vector_type(4)));

// RNE fp32 -> bf16 bit pattern
__device__ __forceinline__ unsigned short f2bf(float f) {
  uint32_t u = __float_as_uint(f);
  u += 0x7fffu + ((u >> 16) & 1u);
  return (unsigned short)(u >> 16);
}

// async global->LDS, 16B per lane. LDS dest is wave-uniform base + lane*16.
__device__ __forceinline__ void load_lds16(const void* g, void* l) {
  __builtin_amdgcn_global_load_lds(
      (__attribute__((address_space(1))) unsigned int*)(uintptr_t)g,
      (__attribute__((address_space(3))) unsigned int*)l,
      16, 0, 0);
}

__device__ __forceinline__ float tanh_fast(float z) {
  // tanh(z) = 1 - 2/(exp(2z)+1); safe for all z
  float e = __expf(z + z);
  return 1.0f - __fdividef(2.0f, e + 1.0f);
}

// aligned LDS vector read (forces ds_read_b128)
__device__ __forceinline__ short8 lds_read8(const unsigned short* p) {
  return *(const short8*)__builtin_assume_aligned(p, 16);
}

// Explicit barrier-with-drain (r16 lesson: the compiler's vmcnt(0)-before-
// s_barrier is observed codegen, not a guarantee; without it one stale LDS
// tile diverged outputs on graph replay). Drain both counters, then barrier.
#define SYNC_DRAIN()                                                   \
  do {                                                                 \
    asm volatile("s_waitcnt vmcnt(0) lgkmcnt(0)" ::: "memory");        \
    __syncthreads();                                                   \
  } while (0)

// ---- fused convert: blocks [0,4096) cast x -> bf16; blocks [4096,5120)
// transpose+cast b (HxH fp32, [k][n]) -> bt bf16 (N x K, [n][k]) ----
__global__ __launch_bounds__(256) void cvt_kernel(const float* __restrict__ x,
                                                  const float* __restrict__ b,
                                                  unsigned short* __restrict__ xbf,
                                                  unsigned short* __restrict__ bt) {
  __shared__ unsigned short tile[64 * 65];
  const int t = threadIdx.x;
  if (blockIdx.x < 4096) {
    size_t i = ((size_t)blockIdx.x * 256 + t) * 8;
    float4 f0 = *(const float4*)(x + i);
    float4 f1 = *(const float4*)(x + i + 4);
    union { unsigned short u[8]; uint4 v; } o;
    o.u[0] = f2bf(f0.x); o.u[1] = f2bf(f0.y); o.u[2] = f2bf(f0.z); o.u[3] = f2bf(f0.w);
    o.u[4] = f2bf(f1.x); o.u[5] = f2bf(f1.y); o.u[6] = f2bf(f1.z); o.u[7] = f2bf(f1.w);
    *(uint4*)(xbf + i) = o.v;
    return;
  }
  const int tb = blockIdx.x - 4096;
  const int bj = tb & 31;  // n block
  const int bi = tb >> 5;  // k block
  {
    const int r0 = t >> 4, c4 = (t & 15) * 4;
#pragma unroll
    for (int p = 0; p < 4; ++p) {
      int r = r0 + p * 16;
      float4 v = *(const float4*)(b + (size_t)(bi * 64 + r) * Hdim + bj * 64 + c4);
      tile[r * 65 + c4 + 0] = f2bf(v.x);
      tile[r * 65 + c4 + 1] = f2bf(v.y);
      tile[r * 65 + c4 + 2] = f2bf(v.z);
      tile[r * 65 + c4 + 3] = f2bf(v.w);
    }
  }
  __syncthreads();
  {
    const int n = t >> 2, kq = (t & 3) * 16;
    union { unsigned short u[16]; uint4 v[2]; } o;
#pragma unroll
    for (int q = 0; q < 16; ++q) o.u[q] = tile[(kq + q) * 65 + n];
    uint4* dst = (uint4*)(bt + (size_t)(bj * 64 + n) * Hdim + bi * 64 + kq);
    dst[0] = o.v[0];
    dst[1] = o.v[1];
  }
}

// ---- GEMM (s = x @ b) with fused windowed-scan epilogue ----
// FINAL (r21 structure; r22/r23 schedule variants both regressed and were
// reverted). Session ledger on the K-loop schedule, all ref-checked:
//   2-phase drain0 (this kernel):      44.9 us  <- best
//   counted-vmcnt monolithic (r23):    49.3 us
//   counted-vmcnt 4-phase (r22):       52.5 us
// In-loop GEMM rate ~900 TF == the measured m97-class 2-barrier structure
// ceiling (learn_hip m99-m141); MfmaUtil 31% == MFMA floor (13.9 us) over
// tile time. Escapes (HK 8-phase co-design) regressed in this fused
// 1-block/CU context: 128 barriers/block with no co-resident block to
// hide them + 8-12-MFMA phases too short to amortize.
//
// Geometry: BM=256 x BN=128, BK=64, 8 waves x 64x64 wave-tile (4x4 frags
// of 16x16x32), 2 LDS buffers, stage->compute->SYNC_DRAIN loop, x2 unroll
// so buffer indices are compile-time. LDS wave-op arithmetic: 8x16
// ds_read_b128 x 12cyc + 50KB DMA ~ 1920 cyc/K-tile vs r17's 3016.
//
// XOR swizzle (proven): slot (row, chunk c) holds global chunk c^(row&7);
// applied on the global fetch column so the wave-uniform contiguous
// global_load_lds dest is preserved; fragment reads XOR the same term ->
// conflict-free ds_read_b128. Rows advance 64 == 0 mod 8 per c-chunk ->
// XOR term constant per thread.
//
// XCD: bm = blockIdx.x (16 values, fastest) -> XCD = bm%8; 2MB of A per
// XCD, L2-resident. Grid 16x16 = 256 blocks = exactly 1/CU.
//
// Warm rows: 8 extra A rows (t0-8..t0-1) staged by wave 7, MFMA'd by
// waves 0,1 (wm==0; wn 0/64, 4 j-frags each = 128 cols) so the scan warms
// up in-block (|a| <= 0.03125 -> influence of h_{t-8} < 1e-12).
// Epilogue: acc -> s_tile (264x129 fp32) -> 512 threads scan 128 cols x
// 4 chunks of 64 rows (8-row warmup each) -> out. No s buffer in HBM.
__global__ __launch_bounds__(512, 2) void gemm_scan_kernel(const unsigned short* __restrict__ A,
                                                           const unsigned short* __restrict__ Bt,
                                                           const float* __restrict__ a_mat,
                                                           float* __restrict__ out) {
  // alignas(16) REQUIRED: otherwise union alignment is 4 and short8 LDS
  // reads split into 4x ds_read_b32 with 16-way conflicts (round-2: 263 us).
  __shared__ alignas(16) union SM {
    struct {
      unsigned short sA[2][256 * 64];   // 2 x 32 KB
      unsigned short sB[2][128 * 64];   // 2 x 16 KB
      unsigned short sAw[2][8 * 64];    // 2 x 1 KB
    } st;                      // 98 KB
    float s_tile[264 * 129];   // 136.2 KB; [row][col], pad 129
  } sm;

  const int tid = threadIdx.x;
  const int bm = blockIdx.x, bn = blockIdx.y;  // bm fastest -> XCD = bm%8
  const int wave = tid >> 6, lane = tid & 63;
  const int wm = (wave >> 1) * 64;   // 0,64,128,192
  const int wn = (wave & 1) * 64;    // 0,64
  const int l15 = lane & 15, quad = lane >> 4;
  const int l7 = l15 & 7;  // row&7 of the rows this lane reads fragments from

  // staging: thread tid fills LDS slot (row = tid>>3 + 64c, chunk = tid&7)
  // holding global chunk (tid&7)^(row&7).
  const int swz = ((tid & 7) ^ ((tid >> 3) & 7)) * 8;
  const unsigned short* aSrc = A + ((size_t)(bm * 256 + (tid >> 3)) * Hdim + swz);
  const unsigned short* bSrc = Bt + ((size_t)(bn * 128 + (tid >> 3)) * Hdim + swz);
  // warm rows staged by wave 7: lane -> row=lane>>3 (8 rows), chunk=lane&7
  const int tw0 = (bm > 0) ? bm * 256 - 8 : 0;  // clamp keeps address valid; bm==0 warm unused
  const int wswz = ((lane & 7) ^ ((lane >> 3) & 7)) * 8;
  const unsigned short* wSrc = A + ((size_t)(tw0 + (lane >> 3)) * Hdim + wswz);

  floatx4 acc[4][4] = {};
  floatx4 accw[4] = {};

  // stage tile (k0) into buffer `buf`: A 4 row-chunks, B 2, warm on wave 7
  auto stage = [&](int buf, int k0) {
    unsigned short* aDst = &sm.st.sA[buf][tid * 8];
    unsigned short* bDst = &sm.st.sB[buf][tid * 8];
#pragma unroll
    for (int c = 0; c < 4; ++c)
      load_lds16(aSrc + (size_t)c * 64 * Hdim + k0, aDst + c * 4096);
#pragma unroll
    for (int c = 0; c < 2; ++c)
      load_lds16(bSrc + (size_t)c * 64 * Hdim + k0, bDst + c * 4096);
    if (wave == 7) load_lds16(wSrc + k0, &sm.st.sAw[buf][lane * 8]);
  };

  // compute from buffer `buf`: wave-tile 64x64 -> 4x4 frags x 2 kk-steps
  auto compute = [&](int buf) {
#pragma unroll
    for (int kk = 0; kk < 64; kk += 32) {
      const int coff = (((kk >> 3) + quad) ^ l7) * 8;
      short8 av[4], bv[4];
#pragma unroll
      for (int i = 0; i < 4; ++i)
        av[i] = lds_read8(&sm.st.sA[buf][(wm + i * 16 + l15) * 64 + coff]);
#pragma unroll
      for (int j = 0; j < 4; ++j)
        bv[j] = lds_read8(&sm.st.sB[buf][(wn + j * 16 + l15) * 64 + coff]);
#pragma unroll
      for (int i = 0; i < 4; ++i)
#pragma unroll
        for (int j = 0; j < 4; ++j)
          acc[i][j] = __builtin_amdgcn_mfma_f32_16x16x32_bf16(av[i], bv[j], acc[i][j], 0, 0, 0);
      if (wm == 0) {  // warm rows: waves 0,1 (wn 0/64), 4 j-frags each
        short8 aw = lds_read8(&sm.st.sAw[buf][l7 * 64 + coff]);
#pragma unroll
        for (int j = 0; j < 4; ++j)
          accw[j] = __builtin_amdgcn_mfma_f32_16x16x32_bf16(aw, bv[j], accw[j], 0, 0, 0);
      }
    }
  };

  // prologue: tile 0 -> buf 0
  stage(0, 0);
  SYNC_DRAIN();
  // main loop, unrolled x2 so buffer indices are compile-time
  for (int it = 0; it < 32; it += 2) {
    stage(1, (it + 1) * 64);          // loads in flight during compute
    compute(0);
    SYNC_DRAIN();                     // drain lands AFTER compute
    if (it + 2 < 32) stage(0, (it + 2) * 64);
    compute(1);
    SYNC_DRAIN();
  }

  // ---- epilogue: registers -> s_tile (C/D layout: col=lane&15, row=quad*4+r) ----
  if (wm == 0 && quad < 2) {  // warm rows idx 0..7 (valid m = 0..7 only)
#pragma unroll
    for (int j = 0; j < 4; ++j)
#pragma unroll
      for (int r = 0; r < 4; ++r)
        sm.s_tile[(quad * 4 + r) * 129 + wn + j * 16 + l15] = accw[j][r];
  }
#pragma unroll
  for (int i = 0; i < 4; ++i)
#pragma unroll
    for (int j = 0; j < 4; ++j)
#pragma unroll
      for (int r = 0; r < 4; ++r)
        sm.s_tile[(8 + wm + i * 16 + quad * 4 + r) * 129 + wn + j * 16 + l15] = acc[i][j][r];
  SYNC_DRAIN();

  // ---- windowed scan: 512 threads = 128 cols x 4 chunks of 64 rows ----
  const int col = tid & 127;
  const int chunk = tid >> 7;
  const float aj = a_mat[bn * 128 + col];
  float h = 0.0f;
  const int row0 = 8 + chunk * 64;
  if (!(bm == 0 && chunk == 0)) {
#pragma unroll
    for (int r = row0 - 8; r < row0; ++r)  // warm-up (discarded outputs)
      h = tanh_fast(fmaf(aj, h, sm.s_tile[r * 129 + col]));
  }
  const size_t gbase = (size_t)(bm * 256 + chunk * 64) * Hdim + bn * 128 + col;
#pragma unroll 4
  for (int r2 = 0; r2 < 64; ++r2) {
    h = tanh_fast(fmaf(aj, h, sm.s_tile[(row0 + r2) * 129 + col]));
    out[gbase + (size_t)r2 * Hdim] = h;
  }
}

extern "C" void kernel_launch(void* const* d_in, const int* in_sizes, int n_in,
                              void* d_out, int out_size, void* d_ws, size_t ws_size,
                              hipStream_t stream) {
  const float* x = (const float*)d_in[0];
  const float* a = (const float*)d_in[1];
  const float* b = (const float*)d_in[2];
  float* out = (float*)d_out;

  unsigned short* ws = (unsigned short*)d_ws;
  unsigned short* xbf = ws;                                 // 16.8 MB
  unsigned short* btb = xbf + (size_t)Tdim * Hdim;          // 8.4 MB

  hipLaunchKernelGGL(cvt_kernel, dim3(4096 + (Hdim / 64) * (Hdim / 64)), dim3(256), 0, stream,
                     x, b, xbf, btb);
  // grid: x = bm (16, fastest -> XCD = bm%8), y = bn (16); 256 blocks = 1/CU
  hipLaunchKernelGGL(gemm_scan_kernel, dim3(Tdim / 256, Hdim / 128), dim3(512), 0, stream,
                     xbf, btb, a, out);
}